// Round 8
// baseline (245.152 us; speedup 1.0000x reference)
//
#include <hip/hip_runtime.h>

typedef unsigned short u16;
typedef unsigned int   u32;
typedef __attribute__((ext_vector_type(8))) short s16x8;
typedef __attribute__((ext_vector_type(4))) float f32x4;
typedef __attribute__((ext_vector_type(16))) float f32x16;
typedef __attribute__((ext_vector_type(2))) int i32x2;

#define D_MODEL 1024
#define S_LEN   2048
#define BATCH   4
#define HEADS   16
#define DK      64
#define M_TOTAL (BATCH * S_LEN)   // 8192

// Q scale: 1/sqrt(64) * log2(e)  (scores produced in log2 domain for exp2)
#define QSCALE 0.18033688011112042f
// log2(10000)/32
#define ROPE_L2 0.41524101186092029f

__device__ __forceinline__ u16 f2b(float f) {
  u32 u = __float_as_uint(f);
  u32 r = u + 0x7FFFu + ((u >> 16) & 1u);
  return (u16)(r >> 16);
}
// pack two positive floats to bf16x2 (truncation — P weights only)
__device__ __forceinline__ u32 packtrunc(float f0, float f1) {
  return (__float_as_uint(f0) >> 16) | (__float_as_uint(f1) & 0xFFFF0000u);
}
// round-to-nearest pack
__device__ __forceinline__ u32 packrn(float f0, float f1) {
  return (u32)f2b(f0) | ((u32)f2b(f1) << 16);
}

// raw v_exp_f32 (no denorm-fixup sequence; scores bounded |S| << 127)
extern "C" __device__ float __ocml_native_exp2_f32(float);
__device__ __forceinline__ float fexp2(float x) {
#if __has_builtin(__builtin_amdgcn_exp2f)
  return __builtin_amdgcn_exp2f(x);
#else
  return __ocml_native_exp2_f32(x);
#endif
}

// counted waits (compile-time immediates)
template<int N> __device__ __forceinline__ void waitvm() {
  asm volatile("s_waitcnt vmcnt(%0)" :: "n"(N) : "memory");
}
template<int N> __device__ __forceinline__ void waitlgkm() {
  asm volatile("s_waitcnt lgkmcnt(%0)" :: "n"(N) : "memory");
}

// inline-asm ds_read_b128: invisible to the memory legalizer, so no
// compiler-inserted vmcnt(0) against outstanding global_load_lds. Each
// consumer group must sit below an explicit lgkmcnt + sched_barrier(0).
template<int OFF> __device__ __forceinline__ s16x8 ldsr(unsigned a) {
  s16x8 r;
  asm volatile("ds_read_b128 %0, %1 offset:%2" : "=v"(r) : "v"(a), "n"(OFF));
  return r;
}

typedef const __attribute__((address_space(1))) unsigned int* gas_u32p;
typedef __attribute__((address_space(3))) unsigned int* las_u32p;
#define GLL16(gp, lp) __builtin_amdgcn_global_load_lds((gas_u32p)(gp), (las_u32p)(lp), 16, 0, 0)

// ---------------- fp32 -> bf16 convert (x + 4 weight matrices, one launch) ----
__global__ void k_cvt(const float* __restrict__ x,
                      const float* __restrict__ a, const float* __restrict__ b,
                      const float* __restrict__ c, const float* __restrict__ d,
                      u16* __restrict__ Xb, u16* __restrict__ Wb) {
  int i = blockIdx.x * blockDim.x + threadIdx.x;   // 0..3145727 float4 groups
  if (i < 2097152) {
    float4 v = ((const float4*)x)[i];
    ((u32*)Xb)[2 * i]     = packrn(v.x, v.y);
    ((u32*)Xb)[2 * i + 1] = packrn(v.z, v.w);
  } else {
    int j = i - 2097152;                           // 0..1048575
    const float* src = (j < 524288) ? ((j < 262144) ? a : b) : ((j < 786432) ? c : d);
    float4 v = ((const float4*)src)[j & 0x3FFFF];
    ((u32*)Wb)[2 * j]     = packrn(v.x, v.y);
    ((u32*)Wb)[2 * j + 1] = packrn(v.z, v.w);
  }
}

// ---------------- GEMM body: C[m][n] = sum_k A[m][k] * B[n][k]  (K-major bf16)
// Round-8 structure: 128x128 tile, BK=32, ring-2 LDS (32 KB) -> 4 blocks/CU
// at launch_bounds(256,4). Depth-1 prefetch: tile t staged in step t-1 right
// after its ds_reads; waitvm<0> at step-t top waits only those 4 loads, which
// have had a full step (~800 cy >> L2 latency) to land. Hazards: stage(t+1)
// overwrites slot (t-1)&1; every wave at this step's barrier has retired its
// (t-1) reads via lgkmcnt(0) before its last MFMA group. Round-7's proven
// read->stage->counted-lgkm-ladder order is kept verbatim, with the 8-quad
// bank swizzle (source blk = (lane&3)^((lane>>3)&3), read blk = q^((rl>>1)&3)).
// SH is passed in (single 32 KB allocation in the caller kernel — avoids one
// static __shared__ per template instantiation).
template<bool BF16OUT, bool ROPE, bool DUAL>
__device__ __forceinline__ void gemm_body(u16* __restrict__ SH,
                                          const u16* __restrict__ A, const u16* __restrict__ B,
                                          void* __restrict__ C, void* __restrict__ C2,
                                          int bm, int bn, int N, int K, float scale) {
  constexpr int SLOT = 8192;            // elems per ring slot (A 4096 | B 4096)
  const int tid  = threadIdx.x;
  const int lane = tid & 63;
  const int w    = tid >> 6;
  const int wm2  = w >> 1, wn2 = w & 1; // 2x2 wave grid, 64x64 per wave
  const int rl   = lane & 15, q = lane >> 4;

  const int rowS = tid >> 2;                      // 0..63
  const int blkS = (tid & 3) ^ ((lane >> 3) & 3);
  const u16* Asrc = A + (size_t)(bm + rowS) * K + blkS * 8;
  const u16* Bsrc = B + (size_t)(bn + rowS) * K + blkS * 8;

  const unsigned shb = (unsigned)(size_t)(las_u32p)SH;
  const int fbase = rl * 32 + ((q ^ ((rl >> 1) & 3)) * 8);   // elems
  const unsigned aR0 = shb + 2 * (wm2 * 2048 + fbase);
  const unsigned bR0 = shb + 2 * (4096 + wn2 * 2048 + fbase);

  f32x4 acc[4][4];
#pragma unroll
  for (int i = 0; i < 4; i++)
#pragma unroll
    for (int j = 0; j < 4; j++) acc[i][j] = (f32x4){0.f, 0.f, 0.f, 0.f};

  const int nt = K >> 5;   // 32

  auto stage = [&](int t) {
    const int k0 = t << 5;
    u16* d = SH + (t & 1) * SLOT + w * 512;   // wave-uniform; HW adds lane*16B
    GLL16(Asrc + k0, d);
    GLL16(Asrc + (size_t)64 * K + k0, d + 2048);
    GLL16(Bsrc + k0, d + 4096);
    GLL16(Bsrc + (size_t)64 * K + k0, d + 6144);
  };

  stage(0);

  for (int t = 0; t < nt; t++) {
    waitvm<0>();                          // own tile-t loads landed (issued 1 step ago)
    __builtin_amdgcn_s_barrier();         // all waves' tile-t loads landed

    const unsigned off = (unsigned)((t & 1) * (2 * SLOT));   // byte offset of slot
    const unsigned aR = aR0 + off, bR = bR0 + off;
    // reads in wait order: bf0..bf3, af0..af3 (asm volatile keeps order)
    s16x8 bf0 = ldsr<0>(bR),    bf1 = ldsr<1024>(bR);
    s16x8 bf2 = ldsr<2048>(bR), bf3 = ldsr<3072>(bR);
    s16x8 af0 = ldsr<0>(aR),    af1 = ldsr<1024>(aR);
    s16x8 af2 = ldsr<2048>(aR), af3 = ldsr<3072>(aR);

    if (t + 1 < nt) stage(t + 1);         // prefetch under the LDS latency

    waitlgkm<3>();                        // bf0-3 + af0 retired
    __builtin_amdgcn_sched_barrier(0);
    __builtin_amdgcn_s_setprio(1);
    acc[0][0] = __builtin_amdgcn_mfma_f32_16x16x32_bf16(af0, bf0, acc[0][0], 0, 0, 0);
    acc[0][1] = __builtin_amdgcn_mfma_f32_16x16x32_bf16(af0, bf1, acc[0][1], 0, 0, 0);
    acc[0][2] = __builtin_amdgcn_mfma_f32_16x16x32_bf16(af0, bf2, acc[0][2], 0, 0, 0);
    acc[0][3] = __builtin_amdgcn_mfma_f32_16x16x32_bf16(af0, bf3, acc[0][3], 0, 0, 0);
    waitlgkm<2>();                        // + af1
    __builtin_amdgcn_sched_barrier(0);
    acc[1][0] = __builtin_amdgcn_mfma_f32_16x16x32_bf16(af1, bf0, acc[1][0], 0, 0, 0);
    acc[1][1] = __builtin_amdgcn_mfma_f32_16x16x32_bf16(af1, bf1, acc[1][1], 0, 0, 0);
    acc[1][2] = __builtin_amdgcn_mfma_f32_16x16x32_bf16(af1, bf2, acc[1][2], 0, 0, 0);
    acc[1][3] = __builtin_amdgcn_mfma_f32_16x16x32_bf16(af1, bf3, acc[1][3], 0, 0, 0);
    waitlgkm<1>();                        // + af2
    __builtin_amdgcn_sched_barrier(0);
    acc[2][0] = __builtin_amdgcn_mfma_f32_16x16x32_bf16(af2, bf0, acc[2][0], 0, 0, 0);
    acc[2][1] = __builtin_amdgcn_mfma_f32_16x16x32_bf16(af2, bf1, acc[2][1], 0, 0, 0);
    acc[2][2] = __builtin_amdgcn_mfma_f32_16x16x32_bf16(af2, bf2, acc[2][2], 0, 0, 0);
    acc[2][3] = __builtin_amdgcn_mfma_f32_16x16x32_bf16(af2, bf3, acc[2][3], 0, 0, 0);
    waitlgkm<0>();                        // + af3 (all reads retired)
    __builtin_amdgcn_sched_barrier(0);
    acc[3][0] = __builtin_amdgcn_mfma_f32_16x16x32_bf16(af3, bf0, acc[3][0], 0, 0, 0);
    acc[3][1] = __builtin_amdgcn_mfma_f32_16x16x32_bf16(af3, bf1, acc[3][1], 0, 0, 0);
    acc[3][2] = __builtin_amdgcn_mfma_f32_16x16x32_bf16(af3, bf2, acc[3][2], 0, 0, 0);
    acc[3][3] = __builtin_amdgcn_mfma_f32_16x16x32_bf16(af3, bf3, acc[3][3], 0, 0, 0);
    __builtin_amdgcn_s_setprio(0);
  }

  // ---- epilogue ----
  const bool isQ = !DUAL || (bn < D_MODEL);
  u16* Cd = (u16*)(isQ ? C : C2);
  const int bnL = DUAL ? (bn & (D_MODEL - 1)) : bn;
  const float sc = isQ ? scale : 1.0f;

#pragma unroll
  for (int mi = 0; mi < 4; mi++)
#pragma unroll
    for (int ni = 0; ni < 4; ni++) {
      if (ROPE) {
        const int col = bnL + wn2 * 64 + ni * 16 + rl;
        const int fi  = (col & 63) >> 1;
        const float inv = exp2f(-(float)fi * ROPE_L2);
        const bool odd = (rl & 1);
#pragma unroll
        for (int r = 0; r < 4; r++) {
          int grow = bm + wm2 * 64 + mi * 16 + q * 4 + r;
          float own = acc[mi][ni][r];
          float oth = __shfl_xor(own, 1);
          float ang = (float)(grow & (S_LEN - 1)) * inv;
          float sn, cs;
          __sincosf(ang, &sn, &cs);
          float x1 = odd ? oth : own;
          float x2 = odd ? own : oth;
          float res = odd ? (x1 * sn + x2 * cs) : (x1 * cs - x2 * sn);
          acc[mi][ni][r] = res * sc;
        }
      }
#pragma unroll
      for (int r = 0; r < 4; r++) {
        int grow = bm + wm2 * 64 + mi * 16 + q * 4 + r;
        int gcol = bnL + wn2 * 64 + ni * 16 + rl;
        float v = acc[mi][ni][r];
        if (BF16OUT) Cd[(size_t)grow * N + gcol] = f2b(v);
        else         ((float*)Cd)[(size_t)grow * N + gcol] = v;
      }
    }
}

// fused QKV projection: one dispatch, 1536 blocks. Blocks swz<1024 compute the
// dual Q|K GEMM (RoPE epilogue); blocks >=1024 compute V TRANSPOSED (A=Wvb,
// B=Xb, coalesced Vtg writes). Same inner loop, balanced per-block work ->
// smooth scheduling, no 256-block QK tail, one less launch gap.
__launch_bounds__(256, 4)
__global__ void k_qkv(const u16* __restrict__ Xb, const u16* __restrict__ Wqkb,
                      const u16* __restrict__ Wvb,
                      u16* __restrict__ Qb, u16* __restrict__ Kb, u16* __restrict__ Vtg) {
  __shared__ u16 SH[16384];               // 32 KB ring-2, shared by both paths
  const int swz = (blockIdx.x & 7) * 192 + (blockIdx.x >> 3);   // 1536 = 8*192
  if (swz < 1024) {
    gemm_body<true, true, true>(SH, Xb, Wqkb, Qb, Kb,
                                (swz >> 4) * 128, (swz & 15) * 128,
                                D_MODEL, D_MODEL, QSCALE);
  } else {
    const int b2 = swz - 1024;            // 0..511
    gemm_body<true, false, false>(SH, Wvb, Xb, Vtg, Vtg,
                                  (b2 >> 6) * 128, (b2 & 63) * 128,
                                  M_TOTAL, D_MODEL, 1.0f);
  }
}

// output projection: M=8192, N=1024, 512 blocks
__launch_bounds__(256, 4)
__global__ void k_out(const u16* __restrict__ Mh, const u16* __restrict__ Wob,
                      float* __restrict__ out) {
  __shared__ u16 SH[16384];
  const int swz = (blockIdx.x & 7) * 64 + (blockIdx.x >> 3);    // 512 = 8*64
  gemm_body<false, false, false>(SH, Mh, Wob, out, out,
                                 (swz >> 3) * 128, (swz & 7) * 128,
                                 D_MODEL, D_MODEL, 1.0f);
}

// ---------------- flash attention (causal), 32x32 MFMA, single-strip waves ----
// (unchanged from rounds 3-7)
__launch_bounds__(256, 4)
__global__ void k_attn(const u16* __restrict__ Qb, const u16* __restrict__ Kb,
                       const u16* __restrict__ Vtg, u16* __restrict__ Mh) {
  __shared__ u16 SH[128 * 64 + 64 * 128];   // Kl [128][64] | Vt [64][128]; reused for O transpose
  u16* Kl = SH;
  u16* Vt = SH + 128 * 64;
  const int tid  = threadIdx.x;
  const int lane = tid & 63;
  const int w    = tid >> 6;
  const int n    = lane & 31;
  const int h    = lane >> 5;        // lane half
  const int nx   = n & 7;            // read-side swizzle key (== row&7 for our rows)
  // decode: XCD = bid&7; within XCD: 16 u-blocks x 8 (b,h)
  const int bid = blockIdx.x;        // 0..1023
  const int r   = bid >> 3;          // 0..127
  const int u   = r & 15;            // block index within (b,h): 0..15
  const int bh  = (bid & 7) + 8 * (r >> 4);   // 0..63
  const int hd  = bh & 15, b = bh >> 4;
  // wave -> strip: {2u, 2u+1, 62-2u, 63-2u}
  const int s   = (w & 2) ? (62 - 2 * u + (w & 1)) : (2 * u + (w & 1));
  const int rb  = s * 32;            // strip base q-row
  const int ktiles = ((63 - 2 * u) >> 2) + 1;   // driven by heaviest strip
  const size_t kbase = ((size_t)b * S_LEN) * D_MODEL + (size_t)hd * DK;
  const size_t vbase = ((size_t)hd * DK) * M_TOTAL + (size_t)b * S_LEN;

  // XOR-folded LDS read bases (element units)
  const int hx    = ((h ^ nx) << 3);
  const int kidx0 = n * 64  + hx;    // ak addr = Kl + ((kidx0 ^ (ks<<4)) + kt*2048)
  const int vidx0 = n * 128 + hx;    // vf addr = Vt + ((vidx0 ^ (kt*32+c*16)) + dt*4096)

  // Q B-frag (n = q-row = lane&31, k = dk = ks*16 + h*8 + j)
  s16x8 bq[4];
#pragma unroll
  for (int ks = 0; ks < 4; ks++)
    bq[ks] = *(const s16x8*)(Qb + kbase + (size_t)(rb + n) * D_MODEL + ks * 16 + h * 8);

  f32x16 o[2];
#pragma unroll
  for (int dt = 0; dt < 2; dt++)
#pragma unroll
    for (int i = 0; i < 16; i++) o[dt][i] = 0.f;
  float psum = 0.f;

  // ---- staging address state (per-lane, pre-swizzled global source) ----
  const int krow_l = lane >> 3;                       // 0..7
  const int kblk_l = (lane & 7) ^ krow_l;             // swizzled source block
  const u16* KgL = Kb + kbase + (size_t)(w * 32 + krow_l) * D_MODEL + kblk_l * 8;
  u16* KdL = Kl + (w * 32) * 64;                      // wave-uniform dest base
  const int vrow_l = lane >> 4;                       // 0..3
  const int vblk_l = lane & 15;
  const u16* VgL = Vtg + vbase + (size_t)(w * 16 + vrow_l) * M_TOTAL;
  u16* VdL = Vt + (w * 16) * 128;

  for (int t = 0; t < ktiles; t++) {
    const int k0 = t * 128;
    __syncthreads();                 // prior tile's LDS reads complete
#pragma unroll
    for (int i = 0; i < 4; i++)
      GLL16(KgL + (size_t)(k0 + i * 8) * D_MODEL, KdL + i * 8 * 64);
#pragma unroll
    for (int i = 0; i < 4; i++) {
      const int jj = vblk_l ^ ((i * 4 + vrow_l) & 7);
      GLL16(VgL + (size_t)(i * 4) * M_TOTAL + k0 + jj * 8, VdL + i * 4 * 128);
    }
    __syncthreads();                 // compiler drains vmcnt(0) before barrier

#pragma unroll
    for (int kt = 0; kt < 4; kt++) {
      const int k0t = k0 + kt * 32;
      if (k0t > rb + 31) continue;          // strip fully masked for this subtile

      s16x8 ak[4], vf[4];
#pragma unroll
      for (int ks = 0; ks < 4; ks++)
        ak[ks] = *(const s16x8*)(Kl + ((kidx0 ^ (ks << 4)) + kt * 2048));
#pragma unroll
      for (int c = 0; c < 2; c++)
#pragma unroll
        for (int dt = 0; dt < 2; dt++)
          vf[c * 2 + dt] = *(const s16x8*)(Vt + ((vidx0 ^ (kt * 32 + c * 16)) + dt * 4096));

      f32x16 Sc;
#pragma unroll
      for (int i = 0; i < 16; i++) Sc[i] = 0.f;
#pragma unroll
      for (int ks = 0; ks < 4; ks++)
        Sc = __builtin_amdgcn_mfma_f32_32x32x16_bf16(ak[ks], bq[ks], Sc, 0, 0, 0);

      u32 P0[4], P1[4];
      float ps01 = 0.f, ps23 = 0.f;
      if ((k0t + 31) > rb) {
        // diagonal subtile: mask after exp (inline-const select to 0)
        const int lim = rb + n - k0t - 4 * h;   // own keys are 8g+t2 vs lim
#pragma unroll
        for (int g = 0; g < 4; g++) {
          float pv[4];
#pragma unroll
          for (int t2 = 0; t2 < 4; t2++) {
            float e = fexp2(Sc[4 * g + t2]);
            pv[t2] = (8 * g + t2 <= lim) ? e : 0.f;
          }
          ps01 += pv[0] + pv[1];
          ps23 += pv[2] + pv[3];
          P0[g] = packtrunc(pv[0], pv[1]);
          P1[g] = packtrunc(pv[2], pv[3]);
        }
      } else {
#pragma unroll
        for (int g = 0; g < 4; g++) {
          float pv[4];
#pragma unroll
          for (int t2 = 0; t2 < 4; t2++) pv[t2] = fexp2(Sc[4 * g + t2]);
          ps01 += pv[0] + pv[1];
          ps23 += pv[2] + pv[3];
          P0[g] = packtrunc(pv[0], pv[1]);
          P1[g] = packtrunc(pv[2], pv[3]);
        }
      }
      psum += ps01 + ps23;

#pragma unroll
      for (int c = 0; c < 2; c++) {
        // {u0,u2} = swap(P0[2c], P0[2c+1]); {u1,u3} = swap(P1[2c], P1[2c+1])
        i32x2 rA = __builtin_amdgcn_permlane32_swap((int)P0[2 * c], (int)P0[2 * c + 1], false, false);
        i32x2 rB = __builtin_amdgcn_permlane32_swap((int)P1[2 * c], (int)P1[2 * c + 1], false, false);
        union { u32 uu[4]; s16x8 v; } pb;
        pb.uu[0] = (u32)rA[0];
        pb.uu[1] = (u32)rB[0];
        pb.uu[2] = (u32)rA[1];
        pb.uu[3] = (u32)rB[1];
        o[0] = __builtin_amdgcn_mfma_f32_32x32x16_bf16(vf[c * 2 + 0], pb.v, o[0], 0, 0, 0);
        o[1] = __builtin_amdgcn_mfma_f32_32x32x16_bf16(vf[c * 2 + 1], pb.v, o[1], 0, 0, 0);
      }
    }
  }

  // ---- epilogue: through LDS for coalesced stores
  float l = psum + __shfl_xor(psum, 32);
  const float linv = 1.0f / l;
  __syncthreads();
  u16* Olw = SH + w * 32 * 66;      // per-wave [32 qrow][64 dk], stride 66
#pragma unroll
  for (int dt = 0; dt < 2; dt++) {
#pragma unroll
    for (int g = 0; g < 4; g++) {
      u32 lo = packrn(o[dt][4 * g + 0] * linv, o[dt][4 * g + 1] * linv);
      u32 hi = packrn(o[dt][4 * g + 2] * linv, o[dt][4 * g + 3] * linv);
      *(uint2*)(Olw + n * 66 + dt * 32 + 8 * g + 4 * h) = (uint2){lo, hi};
    }
  }
  const int rr = lane >> 3, seg = lane & 7;
#pragma unroll
  for (int ro = 0; ro < 32; ro += 8) {
    uint4 v = *(const uint4*)(Olw + (ro + rr) * 66 + seg * 8);
    *(uint4*)(Mh + ((size_t)b * S_LEN + rb + ro + rr) * D_MODEL + hd * DK + seg * 8) = v;
  }
}

extern "C" void kernel_launch(void* const* d_in, const int* in_sizes, int n_in,
                              void* d_out, int out_size, void* d_ws, size_t ws_size,
                              hipStream_t stream) {
  const float* x  = (const float*)d_in[0];
  const float* Wq = (const float*)d_in[1];
  const float* Wk = (const float*)d_in[2];
  const float* Wv = (const float*)d_in[3];
  const float* Wo = (const float*)d_in[4];
  float* out = (float*)d_out;

  char* ws = (char*)d_ws;
  const size_t xsz = (size_t)M_TOTAL * D_MODEL * 2;
  const size_t wsz = (size_t)D_MODEL * D_MODEL * 2;
  u16* Xb  = (u16*)ws; ws += xsz;
  u16* Wqb = (u16*)ws; ws += wsz;   // Wqb..Wob contiguous (k_cvt + DUAL gemm rely on it)
  u16* Wkb = (u16*)ws; ws += wsz;
  u16* Wvb = (u16*)ws; ws += wsz;
  u16* Wob = (u16*)ws; ws += wsz;
  u16* Qb  = (u16*)ws; ws += xsz;
  u16* Kb  = (u16*)ws; ws += xsz;
  u16* Vtg = (u16*)ws; ws += xsz;   // V transposed: [1024][8192]
  u16* Mh  = (u16*)ws; ws += xsz;

  // converts fused into a single launch: 3145728 float4 groups
  k_cvt<<<12288, 256, 0, stream>>>(x, Wq, Wk, Wv, Wo, Xb, Wqb);

  // fused Q+K (RoPE, dual output) + V-transposed projection, one dispatch
  k_qkv<<<1536, 256, 0, stream>>>(Xb, Wqb, Wvb, Qb, Kb, Vtg);

  k_attn<<<dim3(1024), 256, 0, stream>>>(Qb, Kb, Vtg, Mh);

  // output projection
  k_out<<<512, 256, 0, stream>>>(Mh, Wob, out);
}